// Round 2
// baseline (126.608 us; speedup 1.0000x reference)
//
#include <hip/hip_runtime.h>

#define BLOCK 256
#define MPT 8                          // query points per thread
#define PTS_PER_BLOCK (BLOCK * MPT)    // 2048
#define NCHUNK 16                      // candidate chunks per direction
#define BATCH 4
#define NPTS 8192
#define CHUNK (NPTS / NCHUNK)          // 512 candidates staged per block

typedef _Float16 h2 __attribute__((ext_vector_type(2)));

static __device__ __forceinline__ h2 asH2(float f) {
    union { float f; h2 h; } u; u.f = f; return u.h;
}
static __device__ __forceinline__ float asF(h2 v) {
    union { h2 h; float f; } u; u.h = v; return u.f;
}

#if __has_builtin(__builtin_amdgcn_fdot2)
#define FDOT2(a, b, c) __builtin_amdgcn_fdot2((a), (b), (c), false)
#else
static __device__ __forceinline__ float FDOT2(h2 a, h2 b, float c) {
    return fmaf((float)a.x, (float)b.x, fmaf((float)a.y, (float)b.y, c));
}
#endif

// dir 0: candidates = gt, queries = rec  (min over n for each m  -> loss_1)
// dir 1: candidates = rec, queries = gt  (min over m for each n  -> loss_2)
__global__ __launch_bounds__(BLOCK) void chamfer_min_kernel(
    const float* __restrict__ gt, const float* __restrict__ rec,
    unsigned int* __restrict__ minbuf)
{
    int zc  = blockIdx.z;
    int dir = zc >> 2;        // BATCH == 4
    int b   = zc & 3;
    const float* X = (dir == 0) ? gt : rec;   // candidates
    const float* Y = (dir == 0) ? rec : gt;   // queries
    X += (size_t)b * NPTS * 3;
    Y += (size_t)b * NPTS * 3;

    // Stage candidates quantized to f16: {pack(h0,h1), pack(h2,0), ||h||^2_f32, pad}
    __shared__ float4 xs[CHUNK];
    int c0 = blockIdx.y * CHUNK;
    for (int t = threadIdx.x; t < CHUNK; t += BLOCK) {
        float x0 = X[(c0 + t) * 3 + 0];
        float x1 = X[(c0 + t) * 3 + 1];
        float x2 = X[(c0 + t) * 3 + 2];
        _Float16 hx0 = (_Float16)x0, hx1 = (_Float16)x1, hx2 = (_Float16)x2;
        float f0 = (float)hx0, f1 = (float)hx1, f2 = (float)hx2;
        h2 c01; c01.x = hx0; c01.y = hx1;
        h2 c2z; c2z.x = hx2; c2z.y = (_Float16)0.0f;
        xs[t] = make_float4(asF(c01), asF(c2z), f0 * f0 + f1 * f1 + f2 * f2, 0.0f);
    }
    __syncthreads();

    int q0 = blockIdx.x * PTS_PER_BLOCK + threadIdx.x;
    h2 ny01[MPT], ny2z[MPT];
    float yy[MPT], mn[MPT];
#pragma unroll
    for (int p = 0; p < MPT; ++p) {
        int q = q0 + p * BLOCK;
        float y0 = Y[q * 3 + 0], y1 = Y[q * 3 + 1], y2 = Y[q * 3 + 2];
        _Float16 hy0 = (_Float16)y0, hy1 = (_Float16)y1, hy2 = (_Float16)y2;
        const _Float16 m2 = (_Float16)(-2.0f);
        h2 a; a.x = m2 * hy0; a.y = m2 * hy1; ny01[p] = a;
        h2 c; c.x = m2 * hy2; c.y = (_Float16)0.0f; ny2z[p] = c;
        float g0 = (float)hy0, g1 = (float)hy1, g2 = (float)hy2;
        yy[p] = g0 * g0 + g1 * g1 + g2 * g2;
        mn[p] = 3.0e38f;
    }

    for (int j = 0; j < CHUNK; j += 4) {
        float4 ca = xs[j];
        float4 cb = xs[j + 1];
        float4 cc = xs[j + 2];
        float4 cd = xs[j + 3];
#pragma unroll
        for (int p = 0; p < MPT; ++p) {
            float ta = FDOT2(asH2(ca.x), ny01[p], ca.z);
            ta       = FDOT2(asH2(ca.y), ny2z[p], ta);
            float tb = FDOT2(asH2(cb.x), ny01[p], cb.z);
            tb       = FDOT2(asH2(cb.y), ny2z[p], tb);
            float tc = FDOT2(asH2(cc.x), ny01[p], cc.z);
            tc       = FDOT2(asH2(cc.y), ny2z[p], tc);
            float td = FDOT2(asH2(cd.x), ny01[p], cd.z);
            td       = FDOT2(asH2(cd.y), ny2z[p], td);
            // nested for v_min3 fusion: min3(ta,tb, min3(tc,td,mn))
            mn[p] = fminf(fminf(ta, tb), fminf(fminf(tc, td), mn[p]));
        }
    }

    unsigned int* mb = minbuf + (size_t)(dir * BATCH + b) * NPTS;
#pragma unroll
    for (int p = 0; p < MPT; ++p) {
        // add back ||y~||^2, clamp to >=1e-10 (commutes with min), atomicMin on bits
        float v = fmaxf(mn[p] + yy[p], 1e-10f);
        atomicMin(&mb[q0 + p * BLOCK], __float_as_uint(v));
    }
}

__global__ __launch_bounds__(1024) void chamfer_reduce_kernel(
    const unsigned int* __restrict__ minbuf, float* __restrict__ out)
{
    const int TOT  = 2 * BATCH * NPTS;   // 65536
    const int HALF = BATCH * NPTS;       // 32768
    int tid = threadIdx.x;
    float s0 = 0.f, s1 = 0.f;
    for (int i = tid; i < HALF; i += 1024) s0 += __uint_as_float(minbuf[i]);
    for (int i = HALF + tid; i < TOT; i += 1024) s1 += __uint_as_float(minbuf[i]);
#pragma unroll
    for (int off = 32; off > 0; off >>= 1) {
        s0 += __shfl_down(s0, off, 64);
        s1 += __shfl_down(s1, off, 64);
    }
    __shared__ float w0[16], w1[16];
    int wid = tid >> 6, lane = tid & 63;
    if (lane == 0) { w0[wid] = s0; w1[wid] = s1; }
    __syncthreads();
    if (tid == 0) {
        float a = 0.f, c = 0.f;
        for (int i = 0; i < 16; ++i) { a += w0[i]; c += w1[i]; }
        out[0] = (a / (float)HALF + c / (float)HALF) * 1000.0f;
    }
}

extern "C" void kernel_launch(void* const* d_in, const int* in_sizes, int n_in,
                              void* d_out, int out_size, void* d_ws, size_t ws_size,
                              hipStream_t stream) {
    const float* gt  = (const float*)d_in[0];
    const float* rec = (const float*)d_in[1];
    unsigned int* minbuf = (unsigned int*)d_ws;

    // init minbuf to 0x7F7F7F7F (= 3.39e38 as float) — identity for uint-min
    hipMemsetAsync(minbuf, 0x7F, (size_t)2 * BATCH * NPTS * sizeof(unsigned int), stream);

    dim3 grid(NPTS / PTS_PER_BLOCK, NCHUNK, 2 * BATCH);  // 4 x 16 x 8 = 512 blocks
    chamfer_min_kernel<<<grid, BLOCK, 0, stream>>>(gt, rec, minbuf);
    chamfer_reduce_kernel<<<1, 1024, 0, stream>>>(minbuf, (float*)d_out);
}

// Round 3
// 82.526 us; speedup vs baseline: 1.5342x; 1.5342x over previous
//
#include <hip/hip_runtime.h>

typedef _Float16 half_t;
typedef _Float16 f16x8 __attribute__((ext_vector_type(8)));
typedef float f32x16 __attribute__((ext_vector_type(16)));

#define BATCH 4
#define NPTS 8192
#define NSEG 128                      // n's per block (4 waves x 32)
#define MSEG 2048                     // m's per block
#define CHUNK_M 512                   // m's staged per chunk
#define NTILES 16                     // 32-wide m-tiles per chunk
#define NCHUNKS (MSEG / CHUNK_M)      // 4

// One MFMA computes a 32x32 tile of COMPLETE squared distances via K-embedding:
// A row (gt n):  [gx, gy, gz, nhi, nlo, 1, 1, 0]   (f16, coords quantized)
// B col (rec m): [-2rx,-2ry,-2rz, 1, 1, mhi, mlo, 0]
// dot = -2 g.r + ||g||^2 + ||r||^2  (norms hi/lo-split in f16, err ~1e-6)
__global__ __launch_bounds__(256, 4) void chamfer_mfma_kernel(
    const float* __restrict__ gt, const float* __restrict__ rec,
    unsigned int* __restrict__ minbuf)
{
    const int nseg = blockIdx.x;   // 0..63
    const int mseg = blockIdx.y;   // 0..3
    const int b    = blockIdx.z;   // 0..3
    const float* G = gt  + (size_t)b * NPTS * 3;
    const float* R = rec + (size_t)b * NPTS * 3;
    const int n0 = nseg * NSEG;
    const int m0 = mseg * MSEG;

    const int tid  = threadIdx.x;
    const int lane = tid & 63;
    const int w    = tid >> 6;
    const int lr   = lane & 31;
    const int lh   = lane >> 5;

    __shared__ unsigned int rowbuf[MSEG];        // 8 KB: min over block's n, per m
    __shared__ float bfrag[NTILES][64][4];       // 16 KB: pre-packed B fragments

    for (int i = tid; i < MSEG; i += 256) rowbuf[i] = 0x7F7F7F7Fu;
    // zero the k=8..15 half (lanes 32..63) once; never overwritten
    for (int i = tid; i < NTILES * 32; i += 256) {
        int t = i >> 5, l = (i & 31) + 32;
        bfrag[t][l][0] = 0.f; bfrag[t][l][1] = 0.f;
        bfrag[t][l][2] = 0.f; bfrag[t][l][3] = 0.f;
    }

    // A fragment: wave w owns n's [n0 + w*32, +32). lane: row=lr, k=(lh)*8+e
    f16x8 afrag = {};
    {
        int n = n0 + w * 32 + lr;
        float gx = G[n*3+0], gy = G[n*3+1], gz = G[n*3+2];
        half_t hx = (half_t)gx, hy = (half_t)gy, hz = (half_t)gz;
        float fx = (float)hx, fy = (float)hy, fz = (float)hz;
        float nrm = fx*fx + fy*fy + fz*fz;
        half_t nhi = (half_t)nrm;
        half_t nlo = (half_t)(nrm - (float)nhi);
        if (lh == 0) {
            afrag[0]=hx; afrag[1]=hy; afrag[2]=hz; afrag[3]=nhi;
            afrag[4]=nlo; afrag[5]=(half_t)1.f; afrag[6]=(half_t)1.f;
            afrag[7]=(half_t)0.f;
        }
    }

    f32x16 colacc;
    #pragma unroll
    for (int i = 0; i < 16; ++i) colacc[i] = 3.0e38f;

    const f32x16 zc = {};

    auto process = [&](const f32x16& d, int mbase) {
        #pragma unroll
        for (int i = 0; i < 16; ++i) colacc[i] = fminf(colacc[i], d[i]);
        float a0 = fminf(d[0], d[1]),   a1 = fminf(d[2], d[3]);
        float a2 = fminf(d[4], d[5]),   a3 = fminf(d[6], d[7]);
        float a4 = fminf(d[8], d[9]),   a5 = fminf(d[10], d[11]);
        float a6 = fminf(d[12], d[13]), a7 = fminf(d[14], d[15]);
        float b0 = fminf(a0, a1), b1 = fminf(a2, a3);
        float b2 = fminf(a4, a5), b3 = fminf(a6, a7);
        float rmin = fminf(fminf(b0, b1), fminf(b2, b3));
        atomicMin(&rowbuf[mbase + lr], __float_as_uint(rmin));
    };

    for (int ch = 0; ch < NCHUNKS; ++ch) {
        __syncthreads();
        // stage 512 m-points as packed B-frags (2 per thread)
        #pragma unroll
        for (int s = 0; s < 2; ++s) {
            int j = tid * 2 + s;
            int m = m0 + ch * CHUNK_M + j;
            float rx = R[m*3+0], ry = R[m*3+1], rz = R[m*3+2];
            half_t hx = (half_t)rx, hy = (half_t)ry, hz = (half_t)rz;
            float fx = (float)hx, fy = (float)hy, fz = (float)hz;
            float nrm = fx*fx + fy*fy + fz*fz;
            half_t mhi = (half_t)nrm;
            half_t mlo = (half_t)(nrm - (float)mhi);
            union { half_t h[8]; float4 f4; } u;
            u.h[0] = (half_t)(-2.f*fx); u.h[1] = (half_t)(-2.f*fy);
            u.h[2] = (half_t)(-2.f*fz); u.h[3] = (half_t)1.f;
            u.h[4] = (half_t)1.f;       u.h[5] = mhi;
            u.h[6] = mlo;               u.h[7] = (half_t)0.f;
            int t = j >> 5, c = j & 31;
            *(float4*)&bfrag[t][c][0] = u.f4;
        }
        __syncthreads();

        // software-pipelined: MFMA for tile t while min-processing tile t-1
        f16x8 bf0 = *(const f16x8*)&bfrag[0][lane][0];
        f32x16 dprev = __builtin_amdgcn_mfma_f32_32x32x16_f16(afrag, bf0, zc, 0, 0, 0);
        #pragma unroll
        for (int t = 1; t < NTILES; ++t) {
            f16x8 bft = *(const f16x8*)&bfrag[t][lane][0];
            f32x16 dcur = __builtin_amdgcn_mfma_f32_32x32x16_f16(afrag, bft, zc, 0, 0, 0);
            process(dprev, ch * CHUNK_M + (t - 1) * 32);
            dprev = dcur;
        }
        process(dprev, ch * CHUNK_M + (NTILES - 1) * 32);
    }
    __syncthreads();

    // dir0 (min over n, per m): flush block rowbuf -> global
    unsigned int* mb0 = minbuf + (size_t)b * NPTS;
    for (int i = tid; i < MSEG; i += 256)
        atomicMin(&mb0[m0 + i], rowbuf[i]);

    // dir1 (min over m, per n): cross-lane min over the 32 cols in each half
    #pragma unroll
    for (int i = 0; i < 16; ++i) {
        float v = colacc[i];
        v = fminf(v, __shfl_xor(v, 1));
        v = fminf(v, __shfl_xor(v, 2));
        v = fminf(v, __shfl_xor(v, 4));
        v = fminf(v, __shfl_xor(v, 8));
        v = fminf(v, __shfl_xor(v, 16));
        colacc[i] = v;
    }
    unsigned int* mb1 = minbuf + (size_t)(BATCH + b) * NPTS;
    if (lr == 0) {
        #pragma unroll
        for (int i = 0; i < 16; ++i) {
            int r = (i & 3) + 8 * (i >> 2) + 4 * lh;   // C/D row mapping (m74/m101)
            atomicMin(&mb1[n0 + w * 32 + r], __float_as_uint(colacc[i]));
        }
    }
}

__global__ __launch_bounds__(256) void chamfer_reduce_kernel(
    const unsigned int* __restrict__ minbuf, float* __restrict__ out)
{
    int idx = (blockIdx.x * 256 + threadIdx.x) * 4;
    uint4 v = *(const uint4*)&minbuf[idx];
    float s = fmaxf(__uint_as_float(v.x), 1e-10f)
            + fmaxf(__uint_as_float(v.y), 1e-10f)
            + fmaxf(__uint_as_float(v.z), 1e-10f)
            + fmaxf(__uint_as_float(v.w), 1e-10f);
    #pragma unroll
    for (int off = 32; off > 0; off >>= 1) s += __shfl_down(s, off);
    __shared__ float ws4[4];
    int wv = threadIdx.x >> 6, ln = threadIdx.x & 63;
    if (ln == 0) ws4[wv] = s;
    __syncthreads();
    if (threadIdx.x == 0) {
        float tot = ws4[0] + ws4[1] + ws4[2] + ws4[3];
        atomicAdd(out, tot * (1000.0f / 32768.0f));
    }
}

extern "C" void kernel_launch(void* const* d_in, const int* in_sizes, int n_in,
                              void* d_out, int out_size, void* d_ws, size_t ws_size,
                              hipStream_t stream) {
    const float* gt  = (const float*)d_in[0];
    const float* rec = (const float*)d_in[1];
    unsigned int* minbuf = (unsigned int*)d_ws;

    hipMemsetAsync(minbuf, 0x7F, (size_t)2 * BATCH * NPTS * sizeof(unsigned int), stream);
    hipMemsetAsync(d_out, 0, sizeof(float), stream);

    dim3 grid(NPTS / NSEG, NPTS / MSEG, BATCH);   // 64 x 4 x 4 = 1024 blocks
    chamfer_mfma_kernel<<<grid, 256, 0, stream>>>(gt, rec, minbuf);
    chamfer_reduce_kernel<<<(2 * BATCH * NPTS) / (256 * 4), 256, 0, stream>>>(
        minbuf, (float*)d_out);
}

// Round 4
// 74.813 us; speedup vs baseline: 1.6923x; 1.1031x over previous
//
#include <hip/hip_runtime.h>

typedef _Float16 half_t;
typedef _Float16 f16x4 __attribute__((ext_vector_type(4)));
typedef _Float16 f16x8 __attribute__((ext_vector_type(8)));
typedef float f32x16 __attribute__((ext_vector_type(16)));

#define BATCH 4
#define NPTS 8192
#define NSEG 128                      // n's per block (4 waves x 32)
#define MSEG 2048                     // m's per block
#define CHUNK_M 1024                  // m's staged per chunk
#define NTILES 32                     // 32-wide m-tiles per chunk
#define NCHUNKS (MSEG / CHUNK_M)      // 2

// K=7 embedding in one 32x32x8 MFMA -> complete squared-distance tile:
// A row (gt n):  k0..3 = [gx, gy, gz, nhi]   k4..6 = [nlo, 1, 1]
// B col (rec m): k0..3 = [-2rx,-2ry,-2rz, 1] k4..6 = [1, mhi, mlo]
// dot = -2 g.r + ||g||^2 + ||r||^2   (coords f16-quantized, norms hi/lo f16)
#if __has_builtin(__builtin_amdgcn_mfma_f32_32x32x8f16)
static __device__ __forceinline__ f32x16 MFMA8(f16x4 a, f16x4 b, f32x16 c) {
    return __builtin_amdgcn_mfma_f32_32x32x8f16(a, b, c, 0, 0, 0);
}
#else
// fallback: same per-lane 4 elems at k=lh*8+e for BOTH A and B (a k-permutation
// applied to both operands -> identical dot product)
static __device__ __forceinline__ f32x16 MFMA8(f16x4 a, f16x4 b, f32x16 c) {
    f16x8 a8 = {a[0], a[1], a[2], a[3], (half_t)0.f, (half_t)0.f, (half_t)0.f, (half_t)0.f};
    f16x8 b8 = {b[0], b[1], b[2], b[3], (half_t)0.f, (half_t)0.f, (half_t)0.f, (half_t)0.f};
    return __builtin_amdgcn_mfma_f32_32x32x16_f16(a8, b8, c, 0, 0, 0);
}
#endif

static __device__ __forceinline__ float tree16(const f32x16& d) {
    // min of 16 via v_min3 chains: 5+2+1 = 8 ops after fusion
    float t0 = fminf(fminf(d[0], d[1]), d[2]);
    float t1 = fminf(fminf(d[3], d[4]), d[5]);
    float t2 = fminf(fminf(d[6], d[7]), d[8]);
    float t3 = fminf(fminf(d[9], d[10]), d[11]);
    float t4 = fminf(fminf(d[12], d[13]), d[14]);
    float u0 = fminf(fminf(t0, t1), t2);
    float u1 = fminf(fminf(t3, t4), d[15]);
    return fminf(u0, u1);
}

__global__ __launch_bounds__(256, 4) void chamfer_mfma_kernel(
    const float* __restrict__ gt, const float* __restrict__ rec,
    unsigned int* __restrict__ minbuf)
{
    const int nseg = blockIdx.x;   // 0..63
    const int mseg = blockIdx.y;   // 0..3
    const int b    = blockIdx.z;   // 0..3
    const float* G = gt  + (size_t)b * NPTS * 3;
    const float* R = rec + (size_t)b * NPTS * 3;
    const int n0 = nseg * NSEG;
    const int m0 = mseg * MSEG;

    const int tid  = threadIdx.x;
    const int lane = tid & 63;
    const int w    = tid >> 6;
    const int lr   = lane & 31;
    const int lh   = lane >> 5;

    __shared__ unsigned int rowbuf[MSEG];     // 8 KB: min over block's n, per m
    __shared__ float2 bfrag[NTILES][64];      // 16 KB: packed B fragments (8B/lane)

    for (int i = tid; i < MSEG; i += 256) rowbuf[i] = 0x7F7F7F7Fu;

    // A fragment: wave w owns n's [n0+w*32, +32). lane: row=lr, k=lh*4+e
    f16x4 afrag;
    {
        int n = n0 + w * 32 + lr;
        float gx = G[n*3+0], gy = G[n*3+1], gz = G[n*3+2];
        half_t hx = (half_t)gx, hy = (half_t)gy, hz = (half_t)gz;
        float fx = (float)hx, fy = (float)hy, fz = (float)hz;
        float nrm = fx*fx + fy*fy + fz*fz;
        half_t nhi = (half_t)nrm;
        half_t nlo = (half_t)(nrm - (float)nhi);
        if (lh == 0) { afrag[0]=hx;  afrag[1]=hy;          afrag[2]=hz;          afrag[3]=nhi; }
        else         { afrag[0]=nlo; afrag[1]=(half_t)1.f; afrag[2]=(half_t)1.f; afrag[3]=(half_t)0.f; }
    }

    f32x16 colacc;
    #pragma unroll
    for (int i = 0; i < 16; ++i) colacc[i] = 3.0e38f;
    const f32x16 zc = {};

    // T14 async-stage: prefetch 4 points (6 float2) into regs early
    float2 pref[6];
    auto loadpts = [&](int ch) {
        int m = m0 + ch * CHUNK_M + tid * 4;           // multiple of 4 -> m*3 even
        const float2* p = (const float2*)R + (size_t)(m * 3) / 2;
        #pragma unroll
        for (int k = 0; k < 6; ++k) pref[k] = p[k];
    };
    auto writepack = [&]() {
        float px[4], py[4], pz[4];
        px[0]=pref[0].x; py[0]=pref[0].y; pz[0]=pref[1].x;
        px[1]=pref[1].y; py[1]=pref[2].x; pz[1]=pref[2].y;
        px[2]=pref[3].x; py[2]=pref[3].y; pz[2]=pref[4].x;
        px[3]=pref[4].y; py[3]=pref[5].x; pz[3]=pref[5].y;
        #pragma unroll
        for (int s = 0; s < 4; ++s) {
            int j = tid * 4 + s;
            half_t hx = (half_t)px[s], hy = (half_t)py[s], hz = (half_t)pz[s];
            float fx = (float)hx, fy = (float)hy, fz = (float)hz;
            float nrm = fx*fx + fy*fy + fz*fz;
            half_t mhi = (half_t)nrm;
            half_t mlo = (half_t)(nrm - (float)mhi);
            union { half_t h[4]; float2 f; } u0, u1;
            u0.h[0] = (half_t)(-2.f*fx); u0.h[1] = (half_t)(-2.f*fy);
            u0.h[2] = (half_t)(-2.f*fz); u0.h[3] = (half_t)1.f;
            u1.h[0] = (half_t)1.f; u1.h[1] = mhi; u1.h[2] = mlo; u1.h[3] = (half_t)0.f;
            int t = j >> 5, c = j & 31;
            bfrag[t][c]      = u0.f;   // lanes 0..31  (k=0..3)
            bfrag[t][c + 32] = u1.f;   // lanes 32..63 (k=4..7)
        }
    };

    auto process2 = [&](const f32x16& da, const f32x16& db, int mba, int mbb) {
        #pragma unroll
        for (int i = 0; i < 16; ++i)
            colacc[i] = fminf(fminf(colacc[i], da[i]), db[i]);   // v_min3
        atomicMin(&rowbuf[mba + lr], __float_as_uint(tree16(da)));
        atomicMin(&rowbuf[mbb + lr], __float_as_uint(tree16(db)));
    };

    union { float2 f; f16x4 h; } cv;

    loadpts(0);
    for (int ch = 0; ch < NCHUNKS; ++ch) {
        __syncthreads();              // prior chunk's reads done
        writepack();
        __syncthreads();
        if (ch + 1 < NCHUNKS) loadpts(ch + 1);   // issue early, hide under MFMAs
        const int mbase = ch * CHUNK_M;

        cv.f = bfrag[0][lane]; f16x4 b0 = cv.h;
        cv.f = bfrag[1][lane]; f16x4 b1 = cv.h;
        f32x16 d0 = MFMA8(afrag, b0, zc);
        f32x16 d1 = MFMA8(afrag, b1, zc);
        #pragma unroll
        for (int t = 2; t < NTILES; t += 2) {
            cv.f = bfrag[t][lane];     f16x4 ba = cv.h;
            cv.f = bfrag[t + 1][lane]; f16x4 bb = cv.h;
            f32x16 na = MFMA8(afrag, ba, zc);
            f32x16 nb = MFMA8(afrag, bb, zc);
            process2(d0, d1, mbase + (t - 2) * 32, mbase + (t - 1) * 32);
            d0 = na; d1 = nb;
        }
        process2(d0, d1, mbase + (NTILES - 2) * 32, mbase + (NTILES - 1) * 32);
    }
    __syncthreads();

    // dir0 (min over n, per m): flush block rowbuf -> global
    unsigned int* mb0 = minbuf + (size_t)b * NPTS;
    for (int i = tid; i < MSEG; i += 256)
        atomicMin(&mb0[m0 + i], rowbuf[i]);

    // dir1 (min over m, per n): cross-lane min over the 32 cols in each half
    #pragma unroll
    for (int i = 0; i < 16; ++i) {
        float v = colacc[i];
        v = fminf(v, __shfl_xor(v, 1));
        v = fminf(v, __shfl_xor(v, 2));
        v = fminf(v, __shfl_xor(v, 4));
        v = fminf(v, __shfl_xor(v, 8));
        v = fminf(v, __shfl_xor(v, 16));
        colacc[i] = v;
    }
    unsigned int* mb1 = minbuf + (size_t)(BATCH + b) * NPTS;
    if (lr == 0) {
        #pragma unroll
        for (int i = 0; i < 16; ++i) {
            int r = (i & 3) + 8 * (i >> 2) + 4 * lh;   // C/D row mapping (m74/m101)
            atomicMin(&mb1[n0 + w * 32 + r], __float_as_uint(colacc[i]));
        }
    }
}

__global__ __launch_bounds__(256) void chamfer_init_kernel(
    unsigned int* __restrict__ minbuf, float* __restrict__ out)
{
    int idx = (blockIdx.x * 256 + threadIdx.x) * 4;
    *(uint4*)&minbuf[idx] = make_uint4(0x7F7F7F7Fu, 0x7F7F7F7Fu, 0x7F7F7F7Fu, 0x7F7F7F7Fu);
    if (blockIdx.x == 0 && threadIdx.x == 0) out[0] = 0.0f;
}

__global__ __launch_bounds__(256) void chamfer_reduce_kernel(
    const unsigned int* __restrict__ minbuf, float* __restrict__ out)
{
    int idx = (blockIdx.x * 256 + threadIdx.x) * 4;
    uint4 v = *(const uint4*)&minbuf[idx];
    float s = fmaxf(__uint_as_float(v.x), 1e-10f)
            + fmaxf(__uint_as_float(v.y), 1e-10f)
            + fmaxf(__uint_as_float(v.z), 1e-10f)
            + fmaxf(__uint_as_float(v.w), 1e-10f);
    #pragma unroll
    for (int off = 32; off > 0; off >>= 1) s += __shfl_down(s, off);
    __shared__ float ws4[4];
    int wv = threadIdx.x >> 6, ln = threadIdx.x & 63;
    if (ln == 0) ws4[wv] = s;
    __syncthreads();
    if (threadIdx.x == 0) {
        float tot = ws4[0] + ws4[1] + ws4[2] + ws4[3];
        atomicAdd(out, tot * (1000.0f / 32768.0f));
    }
}

extern "C" void kernel_launch(void* const* d_in, const int* in_sizes, int n_in,
                              void* d_out, int out_size, void* d_ws, size_t ws_size,
                              hipStream_t stream) {
    const float* gt  = (const float*)d_in[0];
    const float* rec = (const float*)d_in[1];
    unsigned int* minbuf = (unsigned int*)d_ws;

    const int TOT = 2 * BATCH * NPTS;   // 65536
    chamfer_init_kernel<<<TOT / (256 * 4), 256, 0, stream>>>(minbuf, (float*)d_out);

    dim3 grid(NPTS / NSEG, NPTS / MSEG, BATCH);   // 64 x 4 x 4 = 1024 blocks
    chamfer_mfma_kernel<<<grid, 256, 0, stream>>>(gt, rec, minbuf);

    chamfer_reduce_kernel<<<TOT / (256 * 4), 256, 0, stream>>>(minbuf, (float*)d_out);
}